// Round 18
// baseline (127.479 us; speedup 1.0000x reference)
//
#include <hip/hip_runtime.h>
#include <hip/hip_bf16.h>

#define F 32
#define Dd 16
#define C 64
#define Kk 8
#define CLIPV (1.0f - 1e-6f)
#define K2 2.8853900817779268f  // 2*log2(e): tanh(z)=1-2/(2^(K2*z)+1)
#define NROWBLK 2048            // 2048 blocks x 64 rows
#define BASIS_BYTES ((size_t)131072 * 256 * 2)  // 67,108,864

typedef short v8s __attribute__((ext_vector_type(8)));
typedef float v4f __attribute__((ext_vector_type(4)));
typedef float v2f __attribute__((ext_vector_type(2)));

// bf16 pack via native casts: compiler fuses pairs into v_cvt_pk_bf16_f32
static __device__ inline unsigned pkbf(float lo, float hi) {
    const unsigned l = __bfloat16_as_ushort(__float2bfloat16(lo));
    const unsigned hh = __bfloat16_as_ushort(__float2bfloat16(hi));
    return l | (hh << 16);
}

// ============================ split path =================================
// k1: pure streaming eval. thread (fe=tid&31, rg=tid>>5) evaluates feature
// fe for rows rb+rg*8..+7; writes bf16 basis row-major to ws:
// wsb[row*256 + fe*8 + k]. No LDS, no barriers; 8 waves/SIMD.
__global__ __launch_bounds__(256, 8) void qkan_eval(
    const float* __restrict__ X,        // [B,32]
    const float* __restrict__ phases,   // [16]
    const float* __restrict__ lcu_w,    // [32,16]
    const float* __restrict__ sscale,   // [32]
    const float* __restrict__ sbias,    // [32]
    unsigned short* __restrict__ wsb)   // [B,256] bf16 basis
{
    const int tid = threadIdx.x;
    const int fe = tid & 31;
    const int rg = tid >> 5;
    const int rb = blockIdx.x * 64;

    // X prefetch (coalesced: lanes 0..31 read one row's 32 floats)
    float xq[8];
    {
        const float* xp = X + (size_t)(rb + rg * 8) * F + fe;
#pragma unroll
        for (int m = 0; m < 8; ++m) xq[m] = xp[m * F];
    }

    // fold Clenshaw table for feature fe into VGPRs
    // K2*z(x) = sum_d a_d T_d(x) + sqrt(1-x^2) * sum_d b_d U_{d-1}(x) + fbias
    v2f cc[16];
    float fbias;
    {
        const float* lwf = lcu_w + fe * Dd;
        float wv[16];
        float asum = 0.f;
#pragma unroll
        for (int d = 0; d < Dd; ++d) {
            wv[d] = lwf[d];
            asum += fabsf(wv[d]);
        }
        const float sc = K2 * sscale[fe] / (asum + 1e-6f);
#pragma unroll
        for (int d = 0; d < Dd; ++d) {
            float sp, cp;
            __sincosf(phases[d], &sp, &cp);
            cc[d][0] = sc * wv[d] * cp;    // a_{d+1}
            cc[d][1] = -sc * wv[d] * sp;   // b_{d+1}
        }
        fbias = K2 * sbias[fe];
    }

#pragma unroll
    for (int m = 0; m < 8; ++m) {
        const int row = rb + rg * 8 + m;
        const float x = __builtin_amdgcn_fmed3f(xq[m], -CLIPV, CLIPV);
        const float s1 = __builtin_amdgcn_sqrtf(__builtin_fmaf(-x, x, 1.f));
        const float tx = x + x;
        const v2f tx2 = {tx, tx};
        v2f w = {0.f, 0.f}, wp = {0.f, 0.f};
#pragma unroll
        for (int j = 15; j >= 0; --j) {
            const v2f wn = __builtin_elementwise_fma(tx2, w, cc[j] - wp);
            wp = w;
            w = wn;
        }
        float z = fbias - wp[0];
        z = __builtin_fmaf(x, w[0], z);
        z = __builtin_fmaf(s1, w[1], z);
        const float e = __builtin_amdgcn_exp2f(z);
        const float rr = __builtin_amdgcn_rcpf(e + 1.f);
        const float t = __builtin_fmaf(-2.f, rr, 1.f);
        const float t2 = t + t;
        const float b1 = t;
        const float b2 = t2 * b1 - 1.f;
        const float b3 = t2 * b2 - b1;
        const float b4 = t2 * b3 - b2;
        const float b5 = t2 * b4 - b3;
        const float b6 = t2 * b5 - b4;
        const float b7 = t2 * b6 - b5;
        uint4 pk;
        pk.x = pkbf(1.f, b1);
        pk.y = pkbf(b2, b3);
        pk.z = pkbf(b4, b5);
        pk.w = pkbf(b6, b7);
        *reinterpret_cast<uint4*>(&wsb[(size_t)row * 256 + fe * 8]) = pk;
    }
}

// k2: LDS-free streaming GEMM. Wave wu owns classes [16wu,16wu+16);
// A-fragments read directly from ws (L3/L2-resident); B in 32 VGPRs.
// MFMA step q, lane quarter h, regs j hold kappa=(4q+h)*8+j (K-perm invariant).
__global__ __launch_bounds__(256, 8) void qkan_gemm(
    const unsigned short* __restrict__ wsb,  // [B,256] bf16 basis
    const float* __restrict__ coeff,         // [64,32,8]
    const float* __restrict__ kbias,         // [64]
    float* __restrict__ out)                 // [B,64]
{
    const int tid = threadIdx.x;
    const int lane = tid & 63;
    const int wu = __builtin_amdgcn_readfirstlane(tid >> 6);
    const int h = lane >> 4;
    const int r16 = lane & 15;
    const int rb = blockIdx.x * 64;

    v8s Bfr[8];
    const int cidx = wu * 16 + r16;
#pragma unroll
    for (int q = 0; q < 8; ++q) {
        const float* gp = coeff + ((size_t)(cidx * F + 4 * q + h) * Kk);
        const float4 g0 = *reinterpret_cast<const float4*>(gp);
        const float4 g1 = *reinterpret_cast<const float4*>(gp + 4);
        union { unsigned u[4]; v8s v; } bb;
        bb.u[0] = pkbf(g0.x, g0.y);
        bb.u[1] = pkbf(g0.z, g0.w);
        bb.u[2] = pkbf(g1.x, g1.y);
        bb.u[3] = pkbf(g1.z, g1.w);
        Bfr[q] = bb.v;
    }
    const float biasreg = kbias[cidx];

#pragma unroll
    for (int t = 0; t < 4; ++t) {
        const unsigned short* ap = wsb + (size_t)(rb + t * 16 + r16) * 256 + h * 8;
        v4f acc = {biasreg, biasreg, biasreg, biasreg};
#pragma unroll
        for (int q = 0; q < 8; ++q) {
            const v8s a = *reinterpret_cast<const v8s*>(ap + q * 32);
            acc = __builtin_amdgcn_mfma_f32_16x16x32_bf16(a, Bfr[q], acc, 0, 0, 0);
        }
        const int row0 = rb + t * 16 + h * 4;
#pragma unroll
        for (int i = 0; i < 4; ++i) {
            out[(size_t)(row0 + i) * C + cidx] = acc[i];
        }
    }
}

// ============================ fused fallback (r17) =======================
#define BAR_WRITES() do {                                        \
    asm volatile("s_waitcnt lgkmcnt(0)" ::: "memory");           \
    __builtin_amdgcn_s_barrier();                                \
    asm volatile("" ::: "memory");                               \
} while (0)
#define BAR_READS() do {                                         \
    asm volatile("" ::: "memory");                               \
    __builtin_amdgcn_s_barrier();                                \
    asm volatile("" ::: "memory");                               \
} while (0)

__global__ __launch_bounds__(256, 4) void qkan_fused(
    const float* __restrict__ X, const float* __restrict__ phases,
    const float* __restrict__ lcu_w, const float* __restrict__ sscale,
    const float* __restrict__ sbias, const float* __restrict__ coeff,
    const float* __restrict__ kbias, float* __restrict__ out)
{
    __shared__ unsigned short s_basis[F * 512];
    const int tid = threadIdx.x;
    const int lane = tid & 63;
    const int wu = __builtin_amdgcn_readfirstlane(tid >> 6);
    const int h = lane >> 4;
    const int r16 = lane & 15;
    const int fe = tid & 31;
    const int fe7 = fe & 7;
    const int rg = tid >> 5;
    const int rb0 = blockIdx.x * 128;

    float xq[8];
    {
        const float* xp = X + (size_t)(rb0 + rg * 8) * F + fe;
#pragma unroll
        for (int m = 0; m < 8; ++m) xq[m] = xp[m * F];
    }
    v2f cc[16];
    float fbias;
    {
        const float* lwf = lcu_w + fe * Dd;
        float wv[16];
        float asum = 0.f;
#pragma unroll
        for (int d = 0; d < Dd; ++d) { wv[d] = lwf[d]; asum += fabsf(wv[d]); }
        const float sc = K2 * sscale[fe] / (asum + 1e-6f);
#pragma unroll
        for (int d = 0; d < Dd; ++d) {
            float sp, cp;
            __sincosf(phases[d], &sp, &cp);
            cc[d][0] = sc * wv[d] * cp;
            cc[d][1] = -sc * wv[d] * sp;
        }
        fbias = K2 * sbias[fe];
    }
    v8s Bfr[8];
    const int cidx = wu * 16 + r16;
#pragma unroll
    for (int q = 0; q < 8; ++q) {
        const float* gp = coeff + ((size_t)(cidx * F + 4 * q + h) * Kk);
        const float4 g0 = *reinterpret_cast<const float4*>(gp);
        const float4 g1 = *reinterpret_cast<const float4*>(gp + 4);
        union { unsigned u[4]; v8s v; } bb;
        bb.u[0] = pkbf(g0.x, g0.y); bb.u[1] = pkbf(g0.z, g0.w);
        bb.u[2] = pkbf(g1.x, g1.y); bb.u[3] = pkbf(g1.z, g1.w);
        Bfr[q] = bb.v;
    }
    const float biasreg = kbias[cidx];

    for (int mt = 0; mt < 2; ++mt) {
        const int row_base = rb0 + mt * 64;
        if (mt) BAR_READS();
        float xn[8];
        if (mt + 1 < 2) {
            const float* xp = X + (size_t)(row_base + 64 + rg * 8) * F + fe;
#pragma unroll
            for (int m = 0; m < 8; ++m) xn[m] = xp[m * F];
        }
#pragma unroll
        for (int m = 0; m < 8; ++m) {
            const float x = __builtin_amdgcn_fmed3f(xq[m], -CLIPV, CLIPV);
            const float s1 = __builtin_amdgcn_sqrtf(__builtin_fmaf(-x, x, 1.f));
            const float tx = x + x;
            const v2f tx2 = {tx, tx};
            v2f w = {0.f, 0.f}, wp = {0.f, 0.f};
#pragma unroll
            for (int j = 15; j >= 0; --j) {
                const v2f wn = __builtin_elementwise_fma(tx2, w, cc[j] - wp);
                wp = w; w = wn;
            }
            float z = fbias - wp[0];
            z = __builtin_fmaf(x, w[0], z);
            z = __builtin_fmaf(s1, w[1], z);
            const float e = __builtin_amdgcn_exp2f(z);
            const float rr = __builtin_amdgcn_rcpf(e + 1.f);
            const float t = __builtin_fmaf(-2.f, rr, 1.f);
            const float t2 = t + t;
            const float b1 = t;
            const float b2 = t2 * b1 - 1.f;
            const float b3 = t2 * b2 - b1;
            const float b4 = t2 * b3 - b2;
            const float b5 = t2 * b4 - b3;
            const float b6 = t2 * b5 - b4;
            const float b7 = t2 * b6 - b5;
            uint4 pk;
            pk.x = pkbf(1.f, b1); pk.y = pkbf(b2, b3);
            pk.z = pkbf(b4, b5);  pk.w = pkbf(b6, b7);
            *reinterpret_cast<uint4*>(
                &s_basis[fe * 512 + rg * 64 + ((m ^ fe7) << 3)]) = pk;
        }
        BAR_WRITES();
#pragma unroll
        for (int t = 0; t < 4; ++t) {
            const int s0 = ((t * 16 + r16) ^ h) << 3;
            v4f acc = {biasreg, biasreg, biasreg, biasreg};
#pragma unroll
            for (int q = 0; q < 8; ++q) {
                const int idx = (4 * q + h) * 512 + (s0 ^ ((q & 1) << 5));
                const v8s a = *reinterpret_cast<const v8s*>(&s_basis[idx]);
                acc = __builtin_amdgcn_mfma_f32_16x16x32_bf16(a, Bfr[q], acc, 0, 0, 0);
            }
            const int row0 = row_base + t * 16 + h * 4;
#pragma unroll
            for (int i = 0; i < 4; ++i) out[(size_t)(row0 + i) * C + cidx] = acc[i];
        }
        if (mt + 1 < 2) {
#pragma unroll
            for (int m = 0; m < 8; ++m) xq[m] = xn[m];
        }
    }
}

extern "C" void kernel_launch(void* const* d_in, const int* in_sizes, int n_in,
                              void* d_out, int out_size, void* d_ws, size_t ws_size,
                              hipStream_t stream) {
    const float* X  = (const float*)d_in[0];
    const float* ph = (const float*)d_in[1];
    const float* lw = (const float*)d_in[2];
    const float* ss = (const float*)d_in[3];
    const float* sb = (const float*)d_in[4];
    const float* kc = (const float*)d_in[5];
    const float* kb = (const float*)d_in[6];
    float* out = (float*)d_out;

    if (d_ws != nullptr && ws_size >= BASIS_BYTES) {
        unsigned short* wsb = (unsigned short*)d_ws;
        qkan_eval<<<dim3(NROWBLK), dim3(256), 0, stream>>>(X, ph, lw, ss, sb, wsb);
        qkan_gemm<<<dim3(NROWBLK), dim3(256), 0, stream>>>(wsb, kc, kb, out);
    } else {
        qkan_fused<<<dim3(1024), dim3(256), 0, stream>>>(X, ph, lw, ss, sb, kc, kb, out);
    }
}

// Round 19
// 34.843 us; speedup vs baseline: 3.6587x; 3.6587x over previous
//
#include <hip/hip_runtime.h>
#include <hip/hip_bf16.h>

#define F 32
#define Dd 16
#define C 64
#define Kk 8
#define CLIPV (1.0f - 1e-6f)
#define K2 2.8853900817779268f  // 2*log2(e): tanh(z)=1-2/(2^(K2*z)+1)
#define NBLK 1024
#define MT 2              // row-tiles of 64 per block

typedef short v8s __attribute__((ext_vector_type(8)));
typedef float v16f __attribute__((ext_vector_type(16)));
typedef float v2f __attribute__((ext_vector_type(2)));

// bf16 pack via native casts: compiler fuses pairs into v_cvt_pk_bf16_f32
static __device__ inline unsigned pkbf(float lo, float hi) {
    const unsigned l = __bfloat16_as_ushort(__float2bfloat16(lo));
    const unsigned hh = __bfloat16_as_ushort(__float2bfloat16(hi));
    return l | (hh << 16);
}

// LDS-only barriers (no vmcnt drain; X prefetches / stores stay in flight)
#define BAR_WRITES() do {                                        \
    asm volatile("s_waitcnt lgkmcnt(0)" ::: "memory");           \
    __builtin_amdgcn_s_barrier();                                \
    asm volatile("" ::: "memory");                               \
} while (0)
#define BAR_READS() do {                                         \
    asm volatile("" ::: "memory");                               \
    __builtin_amdgcn_s_barrier();                                \
    asm volatile("" ::: "memory");                               \
} while (0)

// r19 = r17 with phase-2 on mfma_f32_32x32x16_bf16 (2x2 wave split):
//  - phase-1 (byte-identical to r17): thread (fe=tid&31, rg=tid>>5) evals
//    feature fe for rows rg*8..+7; Clenshaw table in VGPRs; basis chunk-major
//    in 32 KB LDS, swizzle slot=row^(f&7).
//  - phase-2: wave wu = (row-half rh=wu>>1, class-half ct=wu&1); computes
//    32 rows x 32 classes with 16 MFMAs of 32x32x16 -> each A-fragment feeds
//    32 output cols, halving per-wave LDS reads (32->16 b128 per tile).
//    K-permuted f-major: step q, k-half hh=lane>>5 -> kappa=(2q+hh)*8+j,
//    same lane<->k map on A and B (K-perm invariant).
//  - C/D 32x32 layout: col=lane&31, row=(reg&3)+8*(reg>>2)+4*(lane>>5).
__global__ __launch_bounds__(256) void qkan_kernel(
    const float* __restrict__ X,        // [B,32]
    const float* __restrict__ phases,   // [16]
    const float* __restrict__ lcu_w,    // [32,16]
    const float* __restrict__ sscale,   // [32]
    const float* __restrict__ sbias,    // [32]
    const float* __restrict__ coeff,    // [64,32,8]
    const float* __restrict__ kbias,    // [64]
    float* __restrict__ out)            // [B,64]
{
    __shared__ unsigned short s_basis[F * 512];   // 32768 B exactly

    const int tid = threadIdx.x;
    const int lane = tid & 63;
    const int wu = __builtin_amdgcn_readfirstlane(tid >> 6);
    const int hh = lane >> 5;   // k-half within MFMA
    const int l31 = lane & 31;
    const int fe = tid & 31;    // eval feature
    const int fe7 = fe & 7;
    const int rg = tid >> 5;    // eval row-group (8 rows)

    const int rh = wu >> 1;     // row half (32 rows)
    const int ct = wu & 1;      // class half (32 classes)

    const int rb0 = blockIdx.x * (MT * 64);

    // ---- X prefetch for tile 0: xq[m] = X[rb0+rg*8+m][fe] (coalesced) ----
    float xq[8];
    {
        const float* xp = X + (size_t)(rb0 + rg * 8) * F + fe;
#pragma unroll
        for (int m = 0; m < 8; ++m) xq[m] = xp[m * F];
    }

    // ---- fold Clenshaw table for feature fe into VGPRs (once per kernel) ----
    // K2*z(x) = sum_d a_d T_d(x) + sqrt(1-x^2) * sum_d b_d U_{d-1}(x) + fbias
    v2f cc[16];
    float fbias;
    {
        const float* lwf = lcu_w + fe * Dd;
        float wv[16];
        float asum = 0.f;
#pragma unroll
        for (int d = 0; d < Dd; ++d) {
            wv[d] = lwf[d];
            asum += fabsf(wv[d]);
        }
        const float sc = K2 * sscale[fe] / (asum + 1e-6f);
#pragma unroll
        for (int d = 0; d < Dd; ++d) {
            float sp, cp;
            __sincosf(phases[d], &sp, &cp);
            cc[d][0] = sc * wv[d] * cp;    // a_{d+1}
            cc[d][1] = -sc * wv[d] * sp;   // b_{d+1}
        }
        fbias = K2 * sbias[fe];
    }

    // ---- B fragments: wave covers classes [32ct, 32ct+32) ----
    // step q: lane holds B[kappa=(2q+hh)*8+j][col=l31] = coeff[col][2q+hh][j]
    v8s Bfr[16];
    const int cidx = ct * 32 + l31;
#pragma unroll
    for (int q = 0; q < 16; ++q) {
        const float* gp = coeff + ((size_t)(cidx * F + 2 * q + hh) * Kk);
        const float4 g0 = *reinterpret_cast<const float4*>(gp);
        const float4 g1 = *reinterpret_cast<const float4*>(gp + 4);
        union { unsigned u[4]; v8s v; } bb;
        bb.u[0] = pkbf(g0.x, g0.y);
        bb.u[1] = pkbf(g0.z, g0.w);
        bb.u[2] = pkbf(g1.x, g1.y);
        bb.u[3] = pkbf(g1.z, g1.w);
        Bfr[q] = bb.v;
    }
    const float biasreg = kbias[cidx];

    for (int mt = 0; mt < MT; ++mt) {
        const int row_base = rb0 + mt * 64;
        if (mt) BAR_READS();  // prev phase-2 LDS reads all consumed; no VMEM drain

        // prefetch next tile's X (stays in flight across the barriers)
        float xn[8];
        if (mt + 1 < MT) {
            const float* xp = X + (size_t)(row_base + 64 + rg * 8) * F + fe;
#pragma unroll
            for (int m = 0; m < 8; ++m) xn[m] = xp[m * F];
        }

        // ---- phase 1: 8 independent row-evals of feature fe, table in VGPRs ----
        // swizzled write slot = row ^ fe7  (row = rg*8+m -> rg*8 + (m^fe7))
#pragma unroll
        for (int m = 0; m < 8; ++m) {
            const float x = __builtin_amdgcn_fmed3f(xq[m], -CLIPV, CLIPV);
            const float s1 = __builtin_amdgcn_sqrtf(__builtin_fmaf(-x, x, 1.f));
            const float tx = x + x;
            const v2f tx2 = {tx, tx};
            v2f w = {0.f, 0.f}, wp = {0.f, 0.f};
#pragma unroll
            for (int j = 15; j >= 0; --j) {
                const v2f wn = __builtin_elementwise_fma(tx2, w, cc[j] - wp);
                wp = w;
                w = wn;
            }
            float z = fbias - wp[0];
            z = __builtin_fmaf(x, w[0], z);
            z = __builtin_fmaf(s1, w[1], z);
            const float e = __builtin_amdgcn_exp2f(z);
            const float rr = __builtin_amdgcn_rcpf(e + 1.f);
            const float t = __builtin_fmaf(-2.f, rr, 1.f);
            const float t2 = t + t;
            const float b1 = t;
            const float b2 = t2 * b1 - 1.f;
            const float b3 = t2 * b2 - b1;
            const float b4 = t2 * b3 - b2;
            const float b5 = t2 * b4 - b3;
            const float b6 = t2 * b5 - b4;
            const float b7 = t2 * b6 - b5;
            uint4 pk;
            pk.x = pkbf(1.f, b1);
            pk.y = pkbf(b2, b3);
            pk.z = pkbf(b4, b5);
            pk.w = pkbf(b6, b7);
            *reinterpret_cast<uint4*>(
                &s_basis[fe * 512 + rg * 64 + ((m ^ fe7) << 3)]) = pk;
        }
        BAR_WRITES();  // lgkmcnt(0) only: writes visible; X/stores stay in flight

        // ---- phase 2: 16x mfma_32x32x16, wave = rows [32rh,+32) x classes [32ct,+32) ----
        // A: chunk f=2q+hh, row rh*32+l31, swizzled slot=row^(f&7)
        {
            v16f acc;
#pragma unroll
            for (int r = 0; r < 16; ++r) acc[r] = biasreg;  // bias via MFMA C-in
#pragma unroll
            for (int q = 0; q < 16; ++q) {
                const int f = 2 * q + hh;
                const int slot = (rh * 32 + l31) ^ (f & 7);
                const v8s a = *reinterpret_cast<const v8s*>(
                    &s_basis[f * 512 + slot * 8]);
                acc = __builtin_amdgcn_mfma_f32_32x32x16_bf16(a, Bfr[q], acc, 0, 0, 0);
            }
            // C/D: col=l31, row=(r&3)+8*(r>>2)+4*hh within the 32-row half
            const int row00 = row_base + rh * 32 + 4 * hh;
#pragma unroll
            for (int r = 0; r < 16; ++r) {
                const int rrow = (r & 3) + 8 * (r >> 2);
                out[(size_t)(row00 + rrow) * C + cidx] = acc[r];
            }
        }

        if (mt + 1 < MT) {
#pragma unroll
            for (int m = 0; m < 8; ++m) xq[m] = xn[m];
        }
    }
}

extern "C" void kernel_launch(void* const* d_in, const int* in_sizes, int n_in,
                              void* d_out, int out_size, void* d_ws, size_t ws_size,
                              hipStream_t stream) {
    const float* X  = (const float*)d_in[0];
    const float* ph = (const float*)d_in[1];
    const float* lw = (const float*)d_in[2];
    const float* ss = (const float*)d_in[3];
    const float* sb = (const float*)d_in[4];
    const float* kc = (const float*)d_in[5];
    const float* kb = (const float*)d_in[6];
    float* out = (float*)d_out;
    qkan_kernel<<<dim3(NBLK), dim3(256), 0, stream>>>(X, ph, lw, ss, sb, kc, kb, out);
}

// Round 20
// 25.913 us; speedup vs baseline: 4.9196x; 1.3446x over previous
//
#include <hip/hip_runtime.h>
#include <hip/hip_bf16.h>

#define F 32
#define Dd 16
#define C 64
#define Kk 8
#define CLIPV (1.0f - 1e-6f)
#define K2 2.8853900817779268f  // 2*log2(e): tanh(z)=1-2/(2^(K2*z)+1)
#define NBLK 1024
#define MT 2              // row-tiles of 64 per block

typedef short v8s __attribute__((ext_vector_type(8)));
typedef float v4f __attribute__((ext_vector_type(4)));
typedef float v2f __attribute__((ext_vector_type(2)));

// bf16 pack via native casts: compiler fuses pairs into v_cvt_pk_bf16_f32
static __device__ inline unsigned pkbf(float lo, float hi) {
    const unsigned l = __bfloat16_as_ushort(__float2bfloat16(lo));
    const unsigned hh = __bfloat16_as_ushort(__float2bfloat16(hi));
    return l | (hh << 16);
}

// LDS-only barriers: BAR_WRITES waits own ds_writes (lgkmcnt) then s_barrier;
// BAR_READS is a bare s_barrier (phase-2 ds_reads were all consumed by MFMAs).
// Neither drains vmcnt, so X prefetches / output stores stay in flight.
#define BAR_WRITES() do {                                        \
    asm volatile("s_waitcnt lgkmcnt(0)" ::: "memory");           \
    __builtin_amdgcn_s_barrier();                                \
    asm volatile("" ::: "memory");                               \
} while (0)
#define BAR_READS() do {                                         \
    asm volatile("" ::: "memory");                               \
    __builtin_amdgcn_s_barrier();                                \
    asm volatile("" ::: "memory");                               \
} while (0)

// Structure (r20 = r17 + swapped MFMA operands for coalesced float4 stores):
//  - phase-1 feature-major (unchanged): thread (fe=tid&31, rg=tid>>5) evals
//    feature fe for rows rg*8..+7; Clenshaw table in VGPRs; basis chunk-major
//    in exactly-32KB LDS, swizzle slot=row^(f&7).
//  - phase-2: wave wu owns classes [16wu,16wu+16). A and B fragments of
//    mfma_16x16x32 share the same lane map (idx=lane&15, kgroup=lane>>4), so
//    mfma(Bfr, a, acc) computes D^T: lane = (batchrow=r16), acc regs = 4
//    CONSECUTIVE classes (wu*16+h*4+i) -> epilogue is one dwordx4 store per
//    row-tile (was 4 dword stores), bias rides C-in as a contiguous float4.
__global__ __launch_bounds__(256, 4) void qkan_kernel(
    const float* __restrict__ X,        // [B,32]
    const float* __restrict__ phases,   // [16]
    const float* __restrict__ lcu_w,    // [32,16]
    const float* __restrict__ sscale,   // [32]
    const float* __restrict__ sbias,    // [32]
    const float* __restrict__ coeff,    // [64,32,8]
    const float* __restrict__ kbias,    // [64]
    float* __restrict__ out)            // [B,64]
{
    __shared__ unsigned short s_basis[F * 512];   // 32768 B exactly

    const int tid = threadIdx.x;
    const int lane = tid & 63;
    const int wu = __builtin_amdgcn_readfirstlane(tid >> 6);
    const int h = lane >> 4;
    const int r16 = lane & 15;
    const int fe = tid & 31;   // eval feature
    const int fe7 = fe & 7;
    const int rg = tid >> 5;   // eval row-group (8 rows)

    const int rb0 = blockIdx.x * (MT * 64);

    // ---- X prefetch for tile 0: xq[m] = X[rb0+rg*8+m][fe] (coalesced) ----
    float xq[8];
    {
        const float* xp = X + (size_t)(rb0 + rg * 8) * F + fe;
#pragma unroll
        for (int m = 0; m < 8; ++m) xq[m] = xp[m * F];
    }

    // ---- fold Clenshaw table for feature fe into VGPRs (once per kernel) ----
    // K2*z(x) = sum_d a_d T_d(x) + sqrt(1-x^2) * sum_d b_d U_{d-1}(x) + fbias
    v2f cc[16];
    float fbias;
    {
        const float* lwf = lcu_w + fe * Dd;
        float wv[16];
        float asum = 0.f;
#pragma unroll
        for (int d = 0; d < Dd; ++d) {
            wv[d] = lwf[d];
            asum += fabsf(wv[d]);
        }
        const float sc = K2 * sscale[fe] / (asum + 1e-6f);
#pragma unroll
        for (int d = 0; d < Dd; ++d) {
            float sp, cp;
            __sincosf(phases[d], &sp, &cp);
            cc[d][0] = sc * wv[d] * cp;    // a_{d+1}
            cc[d][1] = -sc * wv[d] * sp;   // b_{d+1}
        }
        fbias = K2 * sbias[fe];
    }

    // ---- coeff fragments: wave wu owns classes [16wu,16wu+16) ----
    // step q: lane holds coeff[wu*16+r16][f=4q+h][j=0..7] -> kappa=(4q+h)*8+j
    // (same lane<->k map on both MFMA operands => K-perm invariant)
    v8s Bfr[8];
    const int cidx = wu * 16 + r16;
#pragma unroll
    for (int q = 0; q < 8; ++q) {
        const float* gp = coeff + ((size_t)(cidx * F + 4 * q + h) * Kk);
        const float4 g0 = *reinterpret_cast<const float4*>(gp);
        const float4 g1 = *reinterpret_cast<const float4*>(gp + 4);
        union { unsigned u[4]; v8s v; } bb;
        bb.u[0] = pkbf(g0.x, g0.y);
        bb.u[1] = pkbf(g0.z, g0.w);
        bb.u[2] = pkbf(g1.x, g1.y);
        bb.u[3] = pkbf(g1.z, g1.w);
        Bfr[q] = bb.v;
    }
    // bias for this lane's 4 consecutive classes (D^T acc regs)
    const float4 bias4 = *reinterpret_cast<const float4*>(kbias + wu * 16 + h * 4);

    for (int mt = 0; mt < MT; ++mt) {
        const int row_base = rb0 + mt * 64;
        if (mt) BAR_READS();  // prev phase-2 LDS reads all consumed; no VMEM drain

        // prefetch next tile's X (stays in flight across the barriers)
        float xn[8];
        if (mt + 1 < MT) {
            const float* xp = X + (size_t)(row_base + 64 + rg * 8) * F + fe;
#pragma unroll
            for (int m = 0; m < 8; ++m) xn[m] = xp[m * F];
        }

        // ---- phase 1: 8 independent row-evals of feature fe, table in VGPRs ----
        // swizzled write slot = row ^ fe7  (row = rg*8+m -> rg*8 + (m^fe7))
#pragma unroll
        for (int m = 0; m < 8; ++m) {
            const float x = __builtin_amdgcn_fmed3f(xq[m], -CLIPV, CLIPV);
            // 1 - x^2 >= ~1.9e-6 after the clip, so raw hardware sqrt is safe
            const float s1 = __builtin_amdgcn_sqrtf(__builtin_fmaf(-x, x, 1.f));
            const float tx = x + x;
            const v2f tx2 = {tx, tx};
            // paired Clenshaw (native packed fma): .x = T-chain, .y = U-chain
            v2f w = {0.f, 0.f}, wp = {0.f, 0.f};
#pragma unroll
            for (int j = 15; j >= 0; --j) {
                const v2f wn = __builtin_elementwise_fma(tx2, w, cc[j] - wp);
                wp = w;
                w = wn;
            }
            float z = fbias - wp[0];
            z = __builtin_fmaf(x, w[0], z);
            z = __builtin_fmaf(s1, w[1], z);
            // tanh via exp2 (K2 pre-folded): t = 1 - 2/(2^z + 1)
            const float e = __builtin_amdgcn_exp2f(z);
            const float rr = __builtin_amdgcn_rcpf(e + 1.f);
            const float t = __builtin_fmaf(-2.f, rr, 1.f);
            // Chebyshev basis T_0..T_7 -> one b128 LDS write (swizzled slot)
            const float t2 = t + t;
            const float b1 = t;
            const float b2 = t2 * b1 - 1.f;
            const float b3 = t2 * b2 - b1;
            const float b4 = t2 * b3 - b2;
            const float b5 = t2 * b4 - b3;
            const float b6 = t2 * b5 - b4;
            const float b7 = t2 * b6 - b5;
            uint4 pk;
            pk.x = pkbf(1.f, b1);
            pk.y = pkbf(b2, b3);
            pk.z = pkbf(b4, b5);
            pk.w = pkbf(b6, b7);
            *reinterpret_cast<uint4*>(
                &s_basis[fe * 512 + rg * 64 + ((m ^ fe7) << 3)]) = pk;
        }
        BAR_WRITES();  // lgkmcnt(0) only: writes visible; X/stores stay in flight

        // ---- phase 2: MFMA (swapped operands -> D^T), float4 stores ----
        // basis read slot = (t*16+r16) ^ ((4q+h)&7) -> idx = ((v^h)<<3) ^ ((q&1)<<5)
#pragma unroll
        for (int t = 0; t < 4; ++t) {
            const int s0 = ((t * 16 + r16) ^ h) << 3;
            v4f acc = {bias4.x, bias4.y, bias4.z, bias4.w};  // bias via MFMA C-in
#pragma unroll
            for (int q = 0; q < 8; ++q) {
                const int idx = (4 * q + h) * 512 + (s0 ^ ((q & 1) << 5));
                const v8s a = *reinterpret_cast<const v8s*>(&s_basis[idx]);
                // A=coeff, B=basis: D[class][batchrow]; lane=batchrow r16,
                // acc regs = classes wu*16+h*4+0..3 (consecutive)
                acc = __builtin_amdgcn_mfma_f32_16x16x32_bf16(Bfr[q], a, acc, 0, 0, 0);
            }
            const int row = row_base + t * 16 + r16;
            *reinterpret_cast<float4*>(&out[(size_t)row * C + wu * 16 + h * 4]) =
                *reinterpret_cast<const float4*>(&acc);
        }

        if (mt + 1 < MT) {
#pragma unroll
            for (int m = 0; m < 8; ++m) xq[m] = xn[m];
        }
    }
}

extern "C" void kernel_launch(void* const* d_in, const int* in_sizes, int n_in,
                              void* d_out, int out_size, void* d_ws, size_t ws_size,
                              hipStream_t stream) {
    const float* X  = (const float*)d_in[0];
    const float* ph = (const float*)d_in[1];
    const float* lw = (const float*)d_in[2];
    const float* ss = (const float*)d_in[3];
    const float* sb = (const float*)d_in[4];
    const float* kc = (const float*)d_in[5];
    const float* kb = (const float*)d_in[6];
    float* out = (float*)d_out;
    qkan_kernel<<<dim3(NBLK), dim3(256), 0, stream>>>(X, ph, lw, ss, sb, kc, kb, out);
}

// Round 21
// 24.864 us; speedup vs baseline: 5.1271x; 1.0422x over previous
//
#include <hip/hip_runtime.h>
#include <hip/hip_bf16.h>

#define F 32
#define Dd 16
#define C 64
#define Kk 8
#define CLIPV (1.0f - 1e-6f)
#define K2 2.8853900817779268f  // 2*log2(e): tanh(z)=1-2/(2^(K2*z)+1)
#define NBLK 1024
#define MT 2              // row-tiles of 64 per block

typedef short v8s __attribute__((ext_vector_type(8)));
typedef float v4f __attribute__((ext_vector_type(4)));
typedef float v2f __attribute__((ext_vector_type(2)));

// bf16 pack via native casts: compiler fuses pairs into v_cvt_pk_bf16_f32
static __device__ inline unsigned pkbf(float lo, float hi) {
    const unsigned l = __bfloat16_as_ushort(__float2bfloat16(lo));
    const unsigned hh = __bfloat16_as_ushort(__float2bfloat16(hi));
    return l | (hh << 16);
}

// LDS-only barriers: BAR_WRITES waits own ds_writes (lgkmcnt) then s_barrier;
// BAR_READS is a bare s_barrier (phase-2 ds_reads were all consumed by MFMAs).
// Neither drains vmcnt, so X prefetches / output stores stay in flight.
#define BAR_WRITES() do {                                        \
    asm volatile("s_waitcnt lgkmcnt(0)" ::: "memory");           \
    __builtin_amdgcn_s_barrier();                                \
    asm volatile("" ::: "memory");                               \
} while (0)
#define BAR_READS() do {                                         \
    asm volatile("" ::: "memory");                               \
    __builtin_amdgcn_s_barrier();                                \
    asm volatile("" ::: "memory");                               \
} while (0)

// Structure (r21 = r17 + shfl-deduped sincos + nontemporal X/out):
//  - phase-1 feature-major: thread (fe=tid&31, rg=tid>>5) evaluates feature fe
//    for rows rg*8..rg*8+7; folded Clenshaw table (33 coeffs) in VGPRs;
//    sincos(phases[d]) computed ONCE per lane (d=lane&15) and distributed via
//    __shfl width-16 (phases are feature-independent -- 16 distinct pairs).
//  - basis LDS 32768 B exactly, swizzle slot=row^(fe&7)
//  - phase-2: wave wu owns classes [16wu,16wu+16), Bfr in VGPRs; bias via
//    MFMA C-in. X loads / out stores carry nontemporal hints (stream-once).
__global__ __launch_bounds__(256, 4) void qkan_kernel(
    const float* __restrict__ X,        // [B,32]
    const float* __restrict__ phases,   // [16]
    const float* __restrict__ lcu_w,    // [32,16]
    const float* __restrict__ sscale,   // [32]
    const float* __restrict__ sbias,    // [32]
    const float* __restrict__ coeff,    // [64,32,8]
    const float* __restrict__ kbias,    // [64]
    float* __restrict__ out)            // [B,64]
{
    __shared__ unsigned short s_basis[F * 512];   // 32768 B exactly

    const int tid = threadIdx.x;
    const int lane = tid & 63;
    const int wu = __builtin_amdgcn_readfirstlane(tid >> 6);
    const int h = lane >> 4;
    const int r16 = lane & 15;
    const int fe = tid & 31;   // eval feature
    const int fe7 = fe & 7;
    const int rg = tid >> 5;   // eval row-group (8 rows)

    const int rb0 = blockIdx.x * (MT * 64);

    // ---- X prefetch for tile 0 (nontemporal: stream-once data) ----
    float xq[8];
    {
        const float* xp = X + (size_t)(rb0 + rg * 8) * F + fe;
#pragma unroll
        for (int m = 0; m < 8; ++m) xq[m] = __builtin_nontemporal_load(xp + m * F);
    }

    // ---- one sincos per lane; pairs distributed by shfl in the fold loop ----
    float sp0, cp0;
    __sincosf(phases[lane & 15], &sp0, &cp0);

    // ---- fold Clenshaw table for feature fe into VGPRs (once per kernel) ----
    // K2*z(x) = sum_d a_d T_d(x) + sqrt(1-x^2) * sum_d b_d U_{d-1}(x) + fbias
    v2f cc[16];
    float fbias;
    {
        const float* lwf = lcu_w + fe * Dd;
        float wv[16];
        float asum = 0.f;
#pragma unroll
        for (int d = 0; d < Dd; ++d) {
            wv[d] = lwf[d];
            asum += fabsf(wv[d]);
        }
        const float sc = K2 * sscale[fe] / (asum + 1e-6f);
#pragma unroll
        for (int d = 0; d < Dd; ++d) {
            const float cpd = __shfl(cp0, d, 16);
            const float spd = __shfl(sp0, d, 16);
            cc[d][0] = sc * wv[d] * cpd;    // a_{d+1}
            cc[d][1] = -sc * wv[d] * spd;   // b_{d+1}
        }
        fbias = K2 * sbias[fe];
    }

    // ---- B fragments: wave wu owns classes [16wu,16wu+16) ----
    // MFMA step q, lane quarter h, regs j hold phys kappa=(4q+h)*8+j,
    // i.e. f=4q+h, cheb-k=j (same lane<->k map on A and B => K-perm invariant)
    v8s Bfr[8];
    const int cidx = wu * 16 + r16;
#pragma unroll
    for (int q = 0; q < 8; ++q) {
        const float* gp = coeff + ((size_t)(cidx * F + 4 * q + h) * Kk);
        const float4 g0 = *reinterpret_cast<const float4*>(gp);
        const float4 g1 = *reinterpret_cast<const float4*>(gp + 4);
        union { unsigned u[4]; v8s v; } bb;
        bb.u[0] = pkbf(g0.x, g0.y);
        bb.u[1] = pkbf(g0.z, g0.w);
        bb.u[2] = pkbf(g1.x, g1.y);
        bb.u[3] = pkbf(g1.z, g1.w);
        Bfr[q] = bb.v;
    }
    const float biasreg = kbias[cidx];

    for (int mt = 0; mt < MT; ++mt) {
        const int row_base = rb0 + mt * 64;
        if (mt) BAR_READS();  // prev phase-2 LDS reads all consumed; no VMEM drain

        // prefetch next tile's X (stays in flight across the barriers)
        float xn[8];
        if (mt + 1 < MT) {
            const float* xp = X + (size_t)(row_base + 64 + rg * 8) * F + fe;
#pragma unroll
            for (int m = 0; m < 8; ++m) xn[m] = __builtin_nontemporal_load(xp + m * F);
        }

        // ---- phase 1: 8 independent row-evals of feature fe, table in VGPRs ----
        // swizzled write slot = row ^ fe7  (row = rg*8+m -> rg*8 + (m^fe7))
#pragma unroll
        for (int m = 0; m < 8; ++m) {
            const float x = __builtin_amdgcn_fmed3f(xq[m], -CLIPV, CLIPV);
            // 1 - x^2 >= ~1.9e-6 after the clip, so raw hardware sqrt is safe
            const float s1 = __builtin_amdgcn_sqrtf(__builtin_fmaf(-x, x, 1.f));
            const float tx = x + x;
            const v2f tx2 = {tx, tx};
            // paired Clenshaw (native packed fma): .x = T-chain, .y = U-chain
            v2f w = {0.f, 0.f}, wp = {0.f, 0.f};
#pragma unroll
            for (int j = 15; j >= 0; --j) {
                const v2f wn = __builtin_elementwise_fma(tx2, w, cc[j] - wp);
                wp = w;
                w = wn;
            }
            float z = fbias - wp[0];
            z = __builtin_fmaf(x, w[0], z);
            z = __builtin_fmaf(s1, w[1], z);
            // tanh via exp2 (K2 pre-folded): t = 1 - 2/(2^z + 1)
            const float e = __builtin_amdgcn_exp2f(z);
            const float rr = __builtin_amdgcn_rcpf(e + 1.f);
            const float t = __builtin_fmaf(-2.f, rr, 1.f);
            // Chebyshev basis T_0..T_7 -> one b128 LDS write (swizzled slot)
            const float t2 = t + t;
            const float b1 = t;
            const float b2 = t2 * b1 - 1.f;
            const float b3 = t2 * b2 - b1;
            const float b4 = t2 * b3 - b2;
            const float b5 = t2 * b4 - b3;
            const float b6 = t2 * b5 - b4;
            const float b7 = t2 * b6 - b5;
            uint4 pk;
            pk.x = pkbf(1.f, b1);
            pk.y = pkbf(b2, b3);
            pk.z = pkbf(b4, b5);
            pk.w = pkbf(b6, b7);
            *reinterpret_cast<uint4*>(
                &s_basis[fe * 512 + rg * 64 + ((m ^ fe7) << 3)]) = pk;
        }
        BAR_WRITES();  // lgkmcnt(0) only: writes visible; X/stores stay in flight

        // ---- phase 2: MFMA, wave wu computes classes [16wu,16wu+16) for 64 rows ----
        // read slot = (t*16+r16) ^ ((4q+h)&7) -> idx = ((v^h)<<3) ^ ((q&1)<<5)
#pragma unroll
        for (int t = 0; t < 4; ++t) {
            const int s0 = ((t * 16 + r16) ^ h) << 3;
            v4f acc = {biasreg, biasreg, biasreg, biasreg};  // bias via MFMA C-in
#pragma unroll
            for (int q = 0; q < 8; ++q) {
                const int idx = (4 * q + h) * 512 + (s0 ^ ((q & 1) << 5));
                const v8s a = *reinterpret_cast<const v8s*>(&s_basis[idx]);
                acc = __builtin_amdgcn_mfma_f32_16x16x32_bf16(a, Bfr[q], acc, 0, 0, 0);
            }
            const int row0 = row_base + t * 16 + h * 4;
#pragma unroll
            for (int i = 0; i < 4; ++i) {
                __builtin_nontemporal_store(acc[i], &out[(size_t)(row0 + i) * C + cidx]);
            }
        }

        if (mt + 1 < MT) {
#pragma unroll
            for (int m = 0; m < 8; ++m) xq[m] = xn[m];
        }
    }
}

extern "C" void kernel_launch(void* const* d_in, const int* in_sizes, int n_in,
                              void* d_out, int out_size, void* d_ws, size_t ws_size,
                              hipStream_t stream) {
    const float* X  = (const float*)d_in[0];
    const float* ph = (const float*)d_in[1];
    const float* lw = (const float*)d_in[2];
    const float* ss = (const float*)d_in[3];
    const float* sb = (const float*)d_in[4];
    const float* kc = (const float*)d_in[5];
    const float* kb = (const float*)d_in[6];
    float* out = (float*)d_out;
    qkan_kernel<<<dim3(NBLK), dim3(256), 0, stream>>>(X, ph, lw, ss, sb, kc, kb, out);
}